// Round 2
// baseline (354.351 us; speedup 1.0000x reference)
//
#include <hip/hip_runtime.h>

// out[c,i] = W[i]^2 * sum_{e: iInd[e]=i} x[c, jInd[e]]   (B=1, C=32)
//
// Pipeline (all in ws):
//  1. transpose x [C,N] -> xt [N,C]          (contiguous 128B per node)
//  2. histogram of iInd                       (int atomics, 200KB counter array)
//  3. exclusive scan -> CSR offsets (+cursor copy), single 1024-thread block
//  4. scatter jInd into CSR order (sorted_j)  (int atomics for positions)
//  5. segment-sum: one 32-lane group per node, register accumulation,
//     single coalesced 128B store, W^2 applied once per node. NO f32 atomics.
//  6. transpose outt [N,C] -> out [C,N]

#define TCH 32

__global__ void transpose_CN_to_NC(const float* __restrict__ x,
                                   float* __restrict__ xt, int N) {
    __shared__ float tile[32][33];
    const int n0 = blockIdx.x * 32;
    const int tx = threadIdx.x;
    const int ty = threadIdx.y;
    const int n = n0 + tx;
    if (n < N) tile[ty][tx] = x[ty * N + n];
    __syncthreads();
    const int nw = n0 + ty;
    if (nw < N) xt[nw * TCH + tx] = tile[tx][ty];
}

__global__ void transpose_NC_to_CN(const float* __restrict__ xt,
                                   float* __restrict__ out, int N) {
    __shared__ float tile[32][33];
    const int n0 = blockIdx.x * 32;
    const int tx = threadIdx.x;
    const int ty = threadIdx.y;
    const int n = n0 + ty;
    if (n < N) tile[ty][tx] = xt[n * TCH + tx];
    __syncthreads();
    const int nr = n0 + tx;
    if (nr < N) out[ty * N + nr] = tile[tx][ty];
}

__global__ void hist_kernel(const int* __restrict__ iInd,
                            int* __restrict__ counts, int E) {
    const int stride = gridDim.x * blockDim.x;
    for (int e = blockIdx.x * blockDim.x + threadIdx.x; e < E; e += stride)
        atomicAdd(&counts[iInd[e]], 1);
}

// Single-block exclusive scan over N counters; writes offsets[0..N] and a
// working copy into cursor[0..N-1].
__global__ void scan_kernel(const int* __restrict__ counts,
                            int* __restrict__ offsets,
                            int* __restrict__ cursor, int N) {
    __shared__ int sums[1024];
    const int T = 1024;
    const int t = threadIdx.x;
    const int ch = (N + T - 1) / T;
    const int lo = min(N, t * ch);
    const int hi = min(N, lo + ch);
    int s = 0;
    for (int k = lo; k < hi; ++k) s += counts[k];
    sums[t] = s;
    __syncthreads();
    // Hillis-Steele inclusive scan in LDS
    for (int off = 1; off < T; off <<= 1) {
        int v = (t >= off) ? sums[t - off] : 0;
        __syncthreads();
        sums[t] += v;
        __syncthreads();
    }
    int run = (t == 0) ? 0 : sums[t - 1];
    for (int k = lo; k < hi; ++k) {
        offsets[k] = run;
        cursor[k] = run;
        run += counts[k];
    }
    if (hi == N) offsets[N] = run;  // all threads past the end write total
}

__global__ void scatter_kernel(const int* __restrict__ iInd,
                               const int* __restrict__ jInd,
                               int* __restrict__ cursor,
                               int* __restrict__ sorted_j, int E) {
    const int stride = gridDim.x * blockDim.x;
    for (int e = blockIdx.x * blockDim.x + threadIdx.x; e < E; e += stride) {
        const int i = iInd[e];
        const int pos = atomicAdd(&cursor[i], 1);
        sorted_j[pos] = jInd[e];
    }
}

// One 32-lane group per node; lane = channel. 4-way unrolled independent
// accumulators to hide gather latency. Single store per node, no atomics.
__global__ void segment_sum(const int* __restrict__ offsets,
                            const int* __restrict__ sorted_j,
                            const float* __restrict__ W,
                            const float* __restrict__ xt,
                            float* __restrict__ outt, int N) {
    const int gid = blockIdx.x * (blockDim.x >> 5) + (threadIdx.x >> 5);
    const int c = threadIdx.x & 31;
    if (gid >= N) return;
    const int beg = offsets[gid];
    const int end = offsets[gid + 1];
    float s0 = 0.f, s1 = 0.f, s2 = 0.f, s3 = 0.f;
    int e = beg;
    for (; e + 4 <= end; e += 4) {
        const int j0 = sorted_j[e + 0];
        const int j1 = sorted_j[e + 1];
        const int j2 = sorted_j[e + 2];
        const int j3 = sorted_j[e + 3];
        s0 += xt[j0 * TCH + c];
        s1 += xt[j1 * TCH + c];
        s2 += xt[j2 * TCH + c];
        s3 += xt[j3 * TCH + c];
    }
    for (; e < end; ++e) s0 += xt[sorted_j[e] * TCH + c];
    const float w = W[gid];
    outt[gid * TCH + c] = (w * w) * ((s0 + s1) + (s2 + s3));
}

// ---- fallback path (ws too small): direct atomic scatter (round-1 kernel) ----
__global__ void edge_scatter_cn(const int* __restrict__ iInd,
                                const int* __restrict__ jInd,
                                const float* __restrict__ W,
                                const float* __restrict__ x,
                                float* __restrict__ out, int E, int N) {
    const long long t = (long long)blockIdx.x * blockDim.x + threadIdx.x;
    const int e = (int)(t >> 5);
    const int c = (int)(t & 31);
    if (e < E) {
        const int i = iInd[e];
        const int j = jInd[e];
        const float w = W[i];
        atomicAdd(&out[c * N + i], w * w * x[c * N + j]);
    }
}

extern "C" void kernel_launch(void* const* d_in, const int* in_sizes, int n_in,
                              void* d_out, int out_size, void* d_ws, size_t ws_size,
                              hipStream_t stream) {
    const float* x    = (const float*)d_in[0];   // [1, C, N]
    const float* W    = (const float*)d_in[1];   // [N]
    const int*   iInd = (const int*)d_in[2];     // [E]
    const int*   jInd = (const int*)d_in[3];     // [E]

    const int N = in_sizes[1];
    const int E = in_sizes[2];
    float* out = (float*)d_out;

    // ws layout (float/int = 4B each), 256B-aligned sections
    const size_t algn = 64;  // elements (256B)
    const size_t xt_elems   = ((size_t)N * TCH + algn - 1) / algn * algn;
    const size_t outt_elems = xt_elems;
    const size_t sj_elems   = ((size_t)E + algn - 1) / algn * algn;
    const size_t cnt_elems  = ((size_t)N + 1 + algn - 1) / algn * algn;
    const size_t need = (xt_elems + outt_elems + sj_elems + 3 * cnt_elems) * 4;

    if (ws_size >= need) {
        float* xt      = (float*)d_ws;
        float* outt    = xt + xt_elems;
        int*   sorted_j = (int*)(outt + outt_elems);
        int*   counts  = sorted_j + sj_elems;
        int*   offsets = counts + cnt_elems;
        int*   cursor  = offsets + cnt_elems;

        const int ntiles = (N + 31) / 32;
        dim3 tb(32, 32);
        transpose_CN_to_NC<<<ntiles, tb, 0, stream>>>(x, xt, N);

        hipMemsetAsync(counts, 0, (size_t)(N + 1) * sizeof(int), stream);
        hist_kernel<<<1024, 256, 0, stream>>>(iInd, counts, E);
        scan_kernel<<<1, 1024, 0, stream>>>(counts, offsets, cursor, N);
        scatter_kernel<<<1024, 256, 0, stream>>>(iInd, jInd, cursor, sorted_j, E);

        const int groups_per_block = 256 / 32;
        const int ssblocks = (N + groups_per_block - 1) / groups_per_block;
        segment_sum<<<ssblocks, 256, 0, stream>>>(offsets, sorted_j, W, xt, outt, N);

        transpose_NC_to_CN<<<ntiles, tb, 0, stream>>>(outt, out, N);
    } else {
        hipMemsetAsync(out, 0, (size_t)out_size * sizeof(float), stream);
        const int threads = 256;
        const long long total = (long long)E * TCH;
        const int blocks = (int)((total + threads - 1) / threads);
        edge_scatter_cn<<<blocks, threads, 0, stream>>>(iInd, jInd, W, x, out, E, N);
    }
}